// Round 21
// baseline (207.260 us; speedup 1.0000x reference)
//
#include <hip/hip_runtime.h>
#include <math.h>

#define B_   64
#define N_   4096
#define F_   512
#define H_   64
#define G_   10
#define PPG_ 410   // ceil(4096/10)

typedef __attribute__((ext_vector_type(8))) short short8v;    // 8 bf16 (4 VGPRs)
typedef __attribute__((ext_vector_type(16))) float f32x16;    // 32x32 MFMA acc

__device__ __forceinline__ unsigned short f2bf(float f) {
    union { float f; unsigned int u; } v; v.f = f;
    const unsigned int u = v.u;
    return (unsigned short)((u + 0x7FFFu + ((u >> 16) & 1u)) >> 16);  // RNE
}
__device__ __forceinline__ float bf2f(unsigned short u) {
    union { unsigned int u; float f; } v; v.u = ((unsigned int)u) << 16;
    return v.f;
}
__device__ __forceinline__ float fast_tanh(float x) {
    return 1.f - 2.f / (__expf(2.f * x) + 1.f);
}

// ---- workspace layout (float offsets) ----
static const size_t OFF_H    = 0;                       // bf16 h [B,N,H] (32MB)
static const size_t OFF_PNUM = 16777216;                // 524288 : pnum[4096][2][64]
static const size_t OFF_PDEN = OFF_PNUM + 524288;       // 4096   : pden[4096]
static const size_t OFF_B1P  = OFF_PDEN + 4096;
static const size_t OFF_B1Q  = OFF_B1P + 4096;
static const size_t OFF_B2P  = OFF_B1Q + 4096;
static const size_t OFF_B2Q  = OFF_B2P + 4096;
static const size_t OFF_WDT  = OFF_B2Q + 4096;          // 16384 floats: WdT bf16
static const size_t OFF_BAR  = OFF_WDT + 16384;         // 2 uint barrier counters

// ============================================================================
// K0: WdT[col][k] = bf16(Wd[k][col])  (64 KB)
// ============================================================================
__global__ __launch_bounds__(256) void k0_wdt(const float* __restrict__ Wd,
                                              unsigned short* __restrict__ WdT)
{
    const int t = blockIdx.x * 256 + threadIdx.x;   // 0..32767
    const int k = t >> 6, c = t & 63;
    WdT[((size_t)c << 9) + k] = f2bf(Wd[t]);
}

// ============================================================================
// K1: R16 GEMM, unchanged (~117us measured; HBM floor 92).
// ============================================================================
__global__ __launch_bounds__(256) void k1_gemm(
    const float* __restrict__ x, const unsigned short* __restrict__ WdT,
    const float* __restrict__ bd, unsigned short* __restrict__ h)
{
    __shared__ __align__(16) unsigned char atile[2 * 8192];  // A bf16 [64][64] x2, swizzled
    __shared__ __align__(16) unsigned char btile[65536];     // Blin[32*2][64][16B]

    const int tid = threadIdx.x;
    const int w   = tid >> 6;       // wave 0..3
    const int l   = tid & 63;
    const int rowb = (w >> 1) << 5; // 0 / 32
    const int lc  = l & 31;
    const int kh  = l >> 5;         // k-half 0/1

    #pragma unroll
    for (int i = 0; i < 16; ++i) {
        const int p = i * 4096 + tid * 16;
        short8v v = *(const short8v*)((const unsigned char*)WdT + p);
        const int col = p >> 10;
        const int k0  = (p >> 1) & 511;
        const int j   = k0 >> 4;
        const int khh = (k0 >> 3) & 1;
        const int dst = ((j << 1) + (col >> 5)) * 1024 + ((khh << 5) + (col & 31)) * 16;
        *(short8v*)(btile + dst) = v;
    }

    const int srow = tid >> 2;
    const int sq   = tid & 3;
    int wo[4];
    #pragma unroll
    for (int j = 0; j < 4; ++j)
        wo[j] = srow * 128 + ((((j << 1) + (sq >> 1)) ^ (srow & 7)) << 4) + ((sq & 1) << 3);

    const int rb  = (rowb + lc) * 128;
    const int rx7 = lc & 7;
    const unsigned char* bbase = btile + (w & 1) * 1024;

    const int mt0 = blockIdx.x * 8;

    #pragma unroll 1
    for (int mt = 0; mt < 8; ++mt) {
        const int m0 = (mt0 + mt) * 64;
        const float* sp = x + (size_t)(m0 + srow) * F_ + sq * 4;

        f32x16 acc;
        #pragma unroll
        for (int i = 0; i < 16; ++i) acc[i] = 0.f;

        float4 px[4];
        #pragma unroll
        for (int j = 0; j < 4; ++j) px[j] = *(const float4*)(sp + j * 16);
        #pragma unroll
        for (int j = 0; j < 4; ++j) {
            ushort4 v;
            v.x = f2bf(px[j].x); v.y = f2bf(px[j].y);
            v.z = f2bf(px[j].z); v.w = f2bf(px[j].w);
            *(ushort4*)(atile + wo[j]) = v;
        }
        __syncthreads();

        int cur = 0;
        #pragma unroll 1
        for (int t = 0; t < 8; ++t) {
            if (t < 7) {
                const float* q = sp + (t + 1) * 64;
                #pragma unroll
                for (int j = 0; j < 4; ++j) px[j] = *(const float4*)(q + j * 16);
            }
            const unsigned char* ab = atile + cur * 8192;
            #pragma unroll
            for (int s = 0; s < 4; ++s) {
                short8v a = *(const short8v*)(ab + rb + (((kh + 2 * s) ^ rx7) << 4));
                short8v b = *(const short8v*)(bbase + (((t * 4 + s) << 1)) * 1024 + l * 16);
                acc = __builtin_amdgcn_mfma_f32_32x32x16_bf16(a, b, acc, 0, 0, 0);
            }
            if (t < 7) {
                unsigned char* wbuf = atile + (cur ^ 1) * 8192;
                #pragma unroll
                for (int j = 0; j < 4; ++j) {
                    ushort4 v;
                    v.x = f2bf(px[j].x); v.y = f2bf(px[j].y);
                    v.z = f2bf(px[j].z); v.w = f2bf(px[j].w);
                    *(ushort4*)(wbuf + wo[j]) = v;
                }
            }
            __syncthreads();
            cur ^= 1;
        }

        const int col = ((w & 1) << 5) + lc;
        const float bcol = bd[col];
        unsigned short* hb = h + (size_t)m0 * H_;
        #pragma unroll
        for (int r = 0; r < 16; ++r) {
            const int row = rowb + (r & 3) + ((r >> 2) << 3) + (kh << 2);
            hb[(size_t)row * H_ + col] = f2bf(acc[r] + bcol);
        }
    }
}

// ============================================================================
// K2a: score head + softmax partials, one h pass (R19-proven, ~15us).
// ============================================================================
__global__ __launch_bounds__(256) void k2a_scores(
    const unsigned short* __restrict__ h,
    const float* __restrict__ Wa1, const float* __restrict__ ba1,
    const float* __restrict__ Wa2, const float* __restrict__ ba2,
    float* __restrict__ pnum, float* __restrict__ pden)
{
    __shared__ __align__(16) float rowbuf[64][68];
    __shared__ __align__(16) float was[2048];        // Wa1 [64][32]
    __shared__ float bas[32], wa2s[32];
    __shared__ float sexp[64];
    __shared__ float rnum[4][2][64];

    const int p = blockIdx.x, tid = threadIdx.x;
    for (int i = tid; i < 2048; i += 256) was[i] = Wa1[i];
    if (tid < 32) { bas[tid] = ba1[tid]; wa2s[tid] = Wa2[tid]; }

    const int sr = tid >> 2;        // row 0..63
    const int q  = tid & 3;
    const int j0 = q * 8;
    const size_t n0 = (size_t)p * 64;

    {
        const unsigned short* src = h + (n0 + sr) * H_ + q * 16;
        short8v v0 = *(const short8v*)(src);
        short8v v1 = *(const short8v*)(src + 8);
        float* dst = &rowbuf[sr][q * 16];
        float4 f0, f1, f2, f3;
        f0.x = bf2f((unsigned short)v0[0]); f0.y = bf2f((unsigned short)v0[1]);
        f0.z = bf2f((unsigned short)v0[2]); f0.w = bf2f((unsigned short)v0[3]);
        f1.x = bf2f((unsigned short)v0[4]); f1.y = bf2f((unsigned short)v0[5]);
        f1.z = bf2f((unsigned short)v0[6]); f1.w = bf2f((unsigned short)v0[7]);
        f2.x = bf2f((unsigned short)v1[0]); f2.y = bf2f((unsigned short)v1[1]);
        f2.z = bf2f((unsigned short)v1[2]); f2.w = bf2f((unsigned short)v1[3]);
        f3.x = bf2f((unsigned short)v1[4]); f3.y = bf2f((unsigned short)v1[5]);
        f3.z = bf2f((unsigned short)v1[6]); f3.w = bf2f((unsigned short)v1[7]);
        *(float4*)(dst)      = f0;
        *(float4*)(dst + 4)  = f1;
        *(float4*)(dst + 8)  = f2;
        *(float4*)(dst + 12) = f3;
    }
    __syncthreads();

    const float4* was4 = (const float4*)was;
    float tac[8];
    #pragma unroll
    for (int u = 0; u < 8; ++u) tac[u] = bas[j0 + u];
    for (int k = 0; k < 64; ++k) {
        const float hv = rowbuf[sr][k];
        const float4 wa = was4[k * 8 + (q << 1)];
        const float4 wb = was4[k * 8 + (q << 1) + 1];
        tac[0] += hv * wa.x; tac[1] += hv * wa.y;
        tac[2] += hv * wa.z; tac[3] += hv * wa.w;
        tac[4] += hv * wb.x; tac[5] += hv * wb.y;
        tac[6] += hv * wb.z; tac[7] += hv * wb.w;
    }
    float part = 0.f;
    #pragma unroll
    for (int u = 0; u < 8; ++u) part += fast_tanh(tac[u]) * wa2s[j0 + u];
    float sa = 0.f;
    for (int k = q * 16; k < q * 16 + 16; ++k) sa += fabsf(rowbuf[sr][k]);
    part += __shfl_xor(part, 1);
    part += __shfl_xor(part, 2);
    sa   += __shfl_xor(sa, 1);
    sa   += __shfl_xor(sa, 2);
    if (q == 0) sexp[sr] = (sa > 0.f) ? __expf(part + ba2[0]) : 0.f;
    __syncthreads();

    if (tid < 64) {
        float e = sexp[tid];
        #pragma unroll
        for (int o = 1; o < 64; o <<= 1) e += __shfl_xor(e, o);
        if (tid == 0) pden[p] = e;
    }

    const int pl   = p & 63;
    const int nb0  = pl * 64;
    const int glo  = nb0 / PPG_;
    const int col  = tid & 63, qq = tid >> 6;
    float acc0 = 0.f, acc1 = 0.f;
    for (int r = qq; r < 64; r += 4) {
        const float e = sexp[r];
        const float v = rowbuf[r][col];
        if ((nb0 + r) / PPG_ == glo) acc0 += e * v; else acc1 += e * v;
    }
    rnum[qq][0][col] = acc0;
    rnum[qq][1][col] = acc1;
    __syncthreads();
    if (tid < 128) {
        const int slot = tid >> 6, c2 = tid & 63;
        pnum[((size_t)p * 2 + slot) * 64 + c2] =
            rnum[0][slot][c2] + rnum[1][slot][c2] + rnum[2][slot][c2] + rnum[3][slot][c2];
    }
}

// ============================================================================
// Device-scope grid barrier: 64 blocks, all co-resident by capacity
// (64 blocks <= 256 CUs). Counters zeroed per-launch via hipMemsetAsync.
// ============================================================================
__device__ __forceinline__ void grid_barrier(unsigned int* bar, int idx) {
    __syncthreads();
    __threadfence();
    if (threadIdx.x == 0) {
        __hip_atomic_fetch_add(&bar[idx], 1u, __ATOMIC_ACQ_REL, __HIP_MEMORY_SCOPE_AGENT);
        while (__hip_atomic_load(&bar[idx], __ATOMIC_ACQUIRE, __HIP_MEMORY_SCOPE_AGENT)
               < (unsigned)B_) {
            __builtin_amdgcn_s_sleep(8);
        }
    }
    __syncthreads();
    __threadfence();
}

// ============================================================================
// K456: fused conv stack, one block per batch; intermediates LDS-resident.
// Phase A: grouped gather + conv1 + res1 -> LDS (y1s, r1s), BN1 partials -> global
// [grid barrier] Phase B: BN1 finalize, z1 -> zs(LDS), conv2 -> y2 in y1s(LDS),
// BN2 partials -> global.  [grid barrier] Phase C: BN2 finalize, pool, logits.
// ============================================================================
__global__ __launch_bounds__(256) void k456_convstack(
    const float* __restrict__ pnum, const float* __restrict__ pden,
    const float* __restrict__ c1w, const float* __restrict__ c1b,
    const float* __restrict__ r1w, const float* __restrict__ r1b,
    const float* __restrict__ bn1g, const float* __restrict__ bn1b,
    const float* __restrict__ c2w, const float* __restrict__ c2b,
    const float* __restrict__ bn2g, const float* __restrict__ bn2b,
    const float* __restrict__ Wc, const float* __restrict__ bc,
    float* __restrict__ b1p, float* __restrict__ b1q,
    float* __restrict__ b2p, float* __restrict__ b2q,
    unsigned int* __restrict__ bar, float* __restrict__ out)
{
    __shared__ __align__(16) float gs[G_][68];       // grouped, halo at 0/65
    __shared__ float cws[30 * 64];
    __shared__ float rws[G_ * 64];
    __shared__ float c1bs[64], r1bs[64];
    __shared__ __align__(16) float y1s[64 * 68];     // y1raw -> later y2raw
    __shared__ __align__(16) float r1s[64 * 68];     // res1
    __shared__ __align__(16) float zs[64][68];       // z1 (halo at 0/65)
    __shared__ float c2ws[192 * 64];
    __shared__ float s1[64], sh1[64], c2bs[64];
    __shared__ float s2[64], sh2[64];
    __shared__ float red[256];
    __shared__ float plv[64];
    __shared__ float dsh;

    const int b = blockIdx.x, tid = threadIdx.x;
    const int o = tid & 63, lq = tid >> 6;

    // ---------------- Phase A: gather grouped + conv1 ----------------
    if (tid < 64) {
        float e = pden[b * 64 + tid];
        #pragma unroll
        for (int oo = 1; oo < 64; oo <<= 1) e += __shfl_xor(e, oo);
        if (tid == 0) dsh = e;
    }
    for (int i = tid; i < 30 * 64; i += 256) {
        const int ik = i >> 6, oo = i & 63;
        cws[i] = c1w[oo * 30 + ik];
    }
    for (int i = tid; i < G_ * 64; i += 256) {
        const int ch = i >> 6, oo = i & 63;
        rws[i] = r1w[oo * G_ + ch];
    }
    if (tid < 64) { c1bs[tid] = c1b[tid]; r1bs[tid] = r1b[tid]; }
    if (tid < G_) { gs[tid][0] = 0.f; gs[tid][65] = 0.f; gs[tid][66] = 0.f; gs[tid][67] = 0.f; }
    if (tid < 64) { zs[tid][0] = 0.f; zs[tid][65] = 0.f; }
    __syncthreads();

    const float inv = 1.f / dsh;
    for (int i = tid; i < 640; i += 256) {
        const int ch = i >> 6, col = i & 63;
        int p_lo = (PPG_ * ch) >> 6;
        int p_hi = (PPG_ * (ch + 1) - 1) >> 6;
        if (p_hi > 63) p_hi = 63;
        float acc = 0.f;
        for (int pl = p_lo; pl <= p_hi; ++pl) {
            const int glo = (pl * 64) / PPG_;
            const int slot = (glo == ch) ? 0 : 1;
            acc += pnum[(((size_t)(b * 64 + pl)) * 2 + slot) * 64 + col];
        }
        gs[ch][1 + col] = acc * inv;
    }
    __syncthreads();

    {
        float acc[16], racc[16];
        #pragma unroll
        for (int s = 0; s < 16; ++s) { acc[s] = c1bs[o]; racc[s] = r1bs[o]; }
        #pragma unroll
        for (int i = 0; i < G_; ++i) {
            const float* row = &gs[i][lq * 16];
            const float4 a0 = *(const float4*)&row[0];
            const float4 a1 = *(const float4*)&row[4];
            const float4 a2 = *(const float4*)&row[8];
            const float4 a3 = *(const float4*)&row[12];
            const float w16 = row[16], w17 = row[17];
            const float win[18] = { a0.x,a0.y,a0.z,a0.w, a1.x,a1.y,a1.z,a1.w,
                                    a2.x,a2.y,a2.z,a2.w, a3.x,a3.y,a3.z,a3.w, w16, w17 };
            const float w0 = cws[(i * 3 + 0) * 64 + o];
            const float w1 = cws[(i * 3 + 1) * 64 + o];
            const float w2 = cws[(i * 3 + 2) * 64 + o];
            const float rw = rws[i * 64 + o];
            #pragma unroll
            for (int s = 0; s < 16; ++s) {
                acc[s]  += win[s] * w0 + win[s + 1] * w1 + win[s + 2] * w2;
                racc[s] += win[s + 1] * rw;
            }
        }
        float psum = 0.f, psq = 0.f;
        #pragma unroll
        for (int s = 0; s < 16; ++s) { psum += acc[s]; psq += acc[s] * acc[s]; }
        float* yo = &y1s[o * 68 + lq * 16];
        float* ro = &r1s[o * 68 + lq * 16];
        #pragma unroll
        for (int s4 = 0; s4 < 4; ++s4) {
            float4 v; v.x = acc[s4*4]; v.y = acc[s4*4+1]; v.z = acc[s4*4+2]; v.w = acc[s4*4+3];
            *(float4*)&yo[s4 * 4] = v;
            float4 u; u.x = racc[s4*4]; u.y = racc[s4*4+1]; u.z = racc[s4*4+2]; u.w = racc[s4*4+3];
            *(float4*)&ro[s4 * 4] = u;
        }
        red[tid] = psum; __syncthreads();
        if (tid < 64) b1p[b * 64 + tid] = red[tid] + red[tid + 64] + red[tid + 128] + red[tid + 192];
        __syncthreads();
        red[tid] = psq; __syncthreads();
        if (tid < 64) b1q[b * 64 + tid] = red[tid] + red[tid + 64] + red[tid + 128] + red[tid + 192];
    }

    grid_barrier(bar, 0);

    // ---------------- Phase B: BN1 finalize + z1 + conv2 ----------------
    if (tid < 64) {
        float sm = 0.f, sq = 0.f;
        for (int blk = 0; blk < 64; ++blk) { sm += b1p[blk * 64 + tid]; sq += b1q[blk * 64 + tid]; }
        const float mean = sm * (1.f / 4096.f);
        const float var  = sq * (1.f / 4096.f) - mean * mean;
        const float sc   = bn1g[tid] * rsqrtf(var + 1e-5f);
        s1[tid] = sc; sh1[tid] = bn1b[tid] - mean * sc;
        c2bs[tid] = c2b[tid];
    }
    for (int i = tid; i < 192 * 64; i += 256) {
        const int ik = i >> 6, oo = i & 63;
        c2ws[i] = c2w[oo * 192 + ik];
    }
    __syncthreads();
    for (int i = tid; i < 4096; i += 256) {
        const int oo = i >> 6, l = i & 63;
        float v = y1s[oo * 68 + l];
        v = fmaxf(0.f, v * s1[oo] + sh1[oo]) + r1s[oo * 68 + l];
        zs[oo][1 + l] = v;
    }
    __syncthreads();

    {
        float acc[16];
        #pragma unroll
        for (int s = 0; s < 16; ++s) acc[s] = c2bs[o];
        #pragma unroll 4
        for (int i = 0; i < 64; ++i) {
            const float* row = &zs[i][lq * 16];
            const float4 a0 = *(const float4*)&row[0];
            const float4 a1 = *(const float4*)&row[4];
            const float4 a2 = *(const float4*)&row[8];
            const float4 a3 = *(const float4*)&row[12];
            const float w16 = row[16], w17 = row[17];
            const float win[18] = { a0.x,a0.y,a0.z,a0.w, a1.x,a1.y,a1.z,a1.w,
                                    a2.x,a2.y,a2.z,a2.w, a3.x,a3.y,a3.z,a3.w, w16, w17 };
            const float w0 = c2ws[(i * 3 + 0) * 64 + o];
            const float w1 = c2ws[(i * 3 + 1) * 64 + o];
            const float w2 = c2ws[(i * 3 + 2) * 64 + o];
            #pragma unroll
            for (int s = 0; s < 16; ++s)
                acc[s] += win[s] * w0 + win[s + 1] * w1 + win[s + 2] * w2;
        }
        float psum = 0.f, psq = 0.f;
        #pragma unroll
        for (int s = 0; s < 16; ++s) { psum += acc[s]; psq += acc[s] * acc[s]; }
        __syncthreads();   // y1s reads (phase B z1) done; safe to overwrite with y2
        float* yo = &y1s[o * 68 + lq * 16];
        #pragma unroll
        for (int s4 = 0; s4 < 4; ++s4) {
            float4 v; v.x = acc[s4*4]; v.y = acc[s4*4+1]; v.z = acc[s4*4+2]; v.w = acc[s4*4+3];
            *(float4*)&yo[s4 * 4] = v;
        }
        red[tid] = psum; __syncthreads();
        if (tid < 64) b2p[b * 64 + tid] = red[tid] + red[tid + 64] + red[tid + 128] + red[tid + 192];
        __syncthreads();
        red[tid] = psq; __syncthreads();
        if (tid < 64) b2q[b * 64 + tid] = red[tid] + red[tid + 64] + red[tid + 128] + red[tid + 192];
    }

    grid_barrier(bar, 1);

    // ---------------- Phase C: BN2 finalize + pool + logits ----------------
    if (tid < 64) {
        float sm = 0.f, sq = 0.f;
        for (int blk = 0; blk < 64; ++blk) { sm += b2p[blk * 64 + tid]; sq += b2q[blk * 64 + tid]; }
        const float mean = sm * (1.f / 4096.f);
        const float var  = sq * (1.f / 4096.f) - mean * mean;
        const float sc   = bn2g[tid] * rsqrtf(var + 1e-5f);
        s2[tid] = sc; sh2[tid] = bn2b[tid] - mean * sc;
    }
    __syncthreads();
    float psum = 0.f;
    #pragma unroll
    for (int s = 0; s < 16; ++s) {
        const int l = lq * 16 + s;
        psum += fmaxf(0.f, y1s[o * 68 + l] * s2[o] + sh2[o]) + zs[o][1 + l];
    }
    red[tid] = psum; __syncthreads();
    if (tid < 64) plv[tid] = (red[tid] + red[tid + 64] + red[tid + 128] + red[tid + 192]) * (1.f / 64.f);
    __syncthreads();
    if (tid < 2) {
        float lg = bc[tid];
        for (int o2 = 0; o2 < 64; ++o2) lg += plv[o2] * Wc[o2 * 2 + tid];
        out[b * 2 + tid] = lg;
    }
}

// ============================================================================
extern "C" void kernel_launch(void* const* d_in, const int* in_sizes, int n_in,
                              void* d_out, int out_size, void* d_ws, size_t ws_size,
                              hipStream_t stream)
{
    (void)in_sizes; (void)n_in; (void)out_size; (void)ws_size;
    const float* x    = (const float*)d_in[0];
    const float* Wd   = (const float*)d_in[1];
    const float* bd   = (const float*)d_in[2];
    const float* Wa1  = (const float*)d_in[3];
    const float* ba1  = (const float*)d_in[4];
    const float* Wa2  = (const float*)d_in[5];
    const float* ba2  = (const float*)d_in[6];
    const float* c1w  = (const float*)d_in[7];
    const float* c1b  = (const float*)d_in[8];
    const float* bn1g = (const float*)d_in[9];
    const float* bn1b = (const float*)d_in[10];
    const float* r1w  = (const float*)d_in[11];
    const float* r1b  = (const float*)d_in[12];
    const float* c2w  = (const float*)d_in[13];
    const float* c2b  = (const float*)d_in[14];
    const float* bn2g = (const float*)d_in[15];
    const float* bn2b = (const float*)d_in[16];
    const float* Wc   = (const float*)d_in[17];
    const float* bc   = (const float*)d_in[18];

    float* ws      = (float*)d_ws;
    unsigned short* h = (unsigned short*)(ws + OFF_H);   // bf16 h
    float* pnum    = ws + OFF_PNUM;
    float* pden    = ws + OFF_PDEN;
    float* b1p     = ws + OFF_B1P;
    float* b1q     = ws + OFF_B1Q;
    float* b2p     = ws + OFF_B2P;
    float* b2q     = ws + OFF_B2Q;
    unsigned short* WdT = (unsigned short*)(ws + OFF_WDT);
    unsigned int* bar   = (unsigned int*)(ws + OFF_BAR);

    // zero the 2 grid-barrier counters (graph-capturable async memset)
    hipMemsetAsync(bar, 0, 2 * sizeof(unsigned int), stream);

    k0_wdt<<<dim3(128), dim3(256), 0, stream>>>(Wd, WdT);
    k1_gemm<<<dim3(512), dim3(256), 0, stream>>>(x, WdT, bd, h);
    k2a_scores<<<dim3((B_ * N_) / 64), dim3(256), 0, stream>>>(h, Wa1, ba1, Wa2, ba2, pnum, pden);
    k456_convstack<<<dim3(B_), dim3(256), 0, stream>>>(
        pnum, pden, c1w, c1b, r1w, r1b, bn1g, bn1b, c2w, c2b, bn2g, bn2b,
        Wc, bc, b1p, b1q, b2p, b2q, bar, (float*)d_out);
}

// Round 22
// 188.592 us; speedup vs baseline: 1.0990x; 1.0990x over previous
//
#include <hip/hip_runtime.h>
#include <math.h>

#define B_   64
#define N_   4096
#define F_   512
#define H_   64
#define G_   10
#define PPG_ 410   // ceil(4096/10)

typedef __attribute__((ext_vector_type(8))) short short8v;    // 8 bf16 (4 VGPRs)
typedef __attribute__((ext_vector_type(16))) float f32x16;    // 32x32 MFMA acc

__device__ __forceinline__ unsigned short f2bf(float f) {
    union { float f; unsigned int u; } v; v.f = f;
    const unsigned int u = v.u;
    return (unsigned short)((u + 0x7FFFu + ((u >> 16) & 1u)) >> 16);  // RNE
}
__device__ __forceinline__ float bf2f(unsigned short u) {
    union { unsigned int u; float f; } v; v.u = ((unsigned int)u) << 16;
    return v.f;
}
__device__ __forceinline__ float fast_tanh(float x) {
    return 1.f - 2.f / (__expf(2.f * x) + 1.f);
}

// ---- workspace layout (float offsets) ----
static const size_t OFF_H    = 0;                       // bf16 h [B,N,H] (32MB)
static const size_t OFF_PNUM = 16777216;                // 524288 : pnum[4096][2][64]
static const size_t OFF_PDEN = OFF_PNUM + 524288;       // 4096   : pden[4096]
static const size_t OFF_B1P  = OFF_PDEN + 4096;
static const size_t OFF_B1Q  = OFF_B1P + 4096;
static const size_t OFF_B2P  = OFF_B1Q + 4096;
static const size_t OFF_B2Q  = OFF_B2P + 4096;
static const size_t OFF_Y1   = OFF_B2Q + 4096;
static const size_t OFF_RES1 = OFF_Y1  + 262144;
static const size_t OFF_Z1   = OFF_RES1+ 262144;
static const size_t OFF_Y2   = OFF_Z1  + 262144;
static const size_t OFF_WDT  = OFF_Y2  + 262144;        // 64KB WdT[col][k] bf16

// ============================================================================
// K0: WdT[col][k] = bf16(Wd[k][col])  (64 KB)
// ============================================================================
__global__ __launch_bounds__(256) void k0_wdt(const float* __restrict__ Wd,
                                              unsigned short* __restrict__ WdT)
{
    const int t = blockIdx.x * 256 + threadIdx.x;   // 0..32767
    const int k = t >> 6, c = t & 63;
    WdT[((size_t)c << 9) + k] = f2bf(Wd[t]);
}

// ============================================================================
// K1: R16 GEMM, unchanged (~117us measured; HBM floor 92).
// ============================================================================
__global__ __launch_bounds__(256) void k1_gemm(
    const float* __restrict__ x, const unsigned short* __restrict__ WdT,
    const float* __restrict__ bd, unsigned short* __restrict__ h)
{
    __shared__ __align__(16) unsigned char atile[2 * 8192];  // A bf16 [64][64] x2, swizzled
    __shared__ __align__(16) unsigned char btile[65536];     // Blin[32*2][64][16B]

    const int tid = threadIdx.x;
    const int w   = tid >> 6;       // wave 0..3
    const int l   = tid & 63;
    const int rowb = (w >> 1) << 5; // 0 / 32
    const int lc  = l & 31;
    const int kh  = l >> 5;         // k-half 0/1

    #pragma unroll
    for (int i = 0; i < 16; ++i) {
        const int p = i * 4096 + tid * 16;
        short8v v = *(const short8v*)((const unsigned char*)WdT + p);
        const int col = p >> 10;
        const int k0  = (p >> 1) & 511;
        const int j   = k0 >> 4;
        const int khh = (k0 >> 3) & 1;
        const int dst = ((j << 1) + (col >> 5)) * 1024 + ((khh << 5) + (col & 31)) * 16;
        *(short8v*)(btile + dst) = v;
    }

    const int srow = tid >> 2;
    const int sq   = tid & 3;
    int wo[4];
    #pragma unroll
    for (int j = 0; j < 4; ++j)
        wo[j] = srow * 128 + ((((j << 1) + (sq >> 1)) ^ (srow & 7)) << 4) + ((sq & 1) << 3);

    const int rb  = (rowb + lc) * 128;
    const int rx7 = lc & 7;
    const unsigned char* bbase = btile + (w & 1) * 1024;

    const int mt0 = blockIdx.x * 8;

    #pragma unroll 1
    for (int mt = 0; mt < 8; ++mt) {
        const int m0 = (mt0 + mt) * 64;
        const float* sp = x + (size_t)(m0 + srow) * F_ + sq * 4;

        f32x16 acc;
        #pragma unroll
        for (int i = 0; i < 16; ++i) acc[i] = 0.f;

        float4 px[4];
        #pragma unroll
        for (int j = 0; j < 4; ++j) px[j] = *(const float4*)(sp + j * 16);
        #pragma unroll
        for (int j = 0; j < 4; ++j) {
            ushort4 v;
            v.x = f2bf(px[j].x); v.y = f2bf(px[j].y);
            v.z = f2bf(px[j].z); v.w = f2bf(px[j].w);
            *(ushort4*)(atile + wo[j]) = v;
        }
        __syncthreads();

        int cur = 0;
        #pragma unroll 1
        for (int t = 0; t < 8; ++t) {
            if (t < 7) {
                const float* q = sp + (t + 1) * 64;
                #pragma unroll
                for (int j = 0; j < 4; ++j) px[j] = *(const float4*)(q + j * 16);
            }
            const unsigned char* ab = atile + cur * 8192;
            #pragma unroll
            for (int s = 0; s < 4; ++s) {
                short8v a = *(const short8v*)(ab + rb + (((kh + 2 * s) ^ rx7) << 4));
                short8v b = *(const short8v*)(bbase + (((t * 4 + s) << 1)) * 1024 + l * 16);
                acc = __builtin_amdgcn_mfma_f32_32x32x16_bf16(a, b, acc, 0, 0, 0);
            }
            if (t < 7) {
                unsigned char* wbuf = atile + (cur ^ 1) * 8192;
                #pragma unroll
                for (int j = 0; j < 4; ++j) {
                    ushort4 v;
                    v.x = f2bf(px[j].x); v.y = f2bf(px[j].y);
                    v.z = f2bf(px[j].z); v.w = f2bf(px[j].w);
                    *(ushort4*)(wbuf + wo[j]) = v;
                }
            }
            __syncthreads();
            cur ^= 1;
        }

        const int col = ((w & 1) << 5) + lc;
        const float bcol = bd[col];
        unsigned short* hb = h + (size_t)m0 * H_;
        #pragma unroll
        for (int r = 0; r < 16; ++r) {
            const int row = rowb + (r & 3) + ((r >> 2) << 3) + (kh << 2);
            hb[(size_t)row * H_ + col] = f2bf(acc[r] + bcol);
        }
    }
}

// ============================================================================
// K2a: score head + softmax partials, one h pass (R19-proven, ~15us).
// ============================================================================
__global__ __launch_bounds__(256) void k2a_scores(
    const unsigned short* __restrict__ h,
    const float* __restrict__ Wa1, const float* __restrict__ ba1,
    const float* __restrict__ Wa2, const float* __restrict__ ba2,
    float* __restrict__ pnum, float* __restrict__ pden)
{
    __shared__ __align__(16) float rowbuf[64][68];
    __shared__ __align__(16) float was[2048];        // Wa1 [64][32]
    __shared__ float bas[32], wa2s[32];
    __shared__ float sexp[64];
    __shared__ float rnum[4][2][64];

    const int p = blockIdx.x, tid = threadIdx.x;
    for (int i = tid; i < 2048; i += 256) was[i] = Wa1[i];
    if (tid < 32) { bas[tid] = ba1[tid]; wa2s[tid] = Wa2[tid]; }

    const int sr = tid >> 2;        // row 0..63
    const int q  = tid & 3;
    const int j0 = q * 8;
    const size_t n0 = (size_t)p * 64;

    {
        const unsigned short* src = h + (n0 + sr) * H_ + q * 16;
        short8v v0 = *(const short8v*)(src);
        short8v v1 = *(const short8v*)(src + 8);
        float* dst = &rowbuf[sr][q * 16];
        float4 f0, f1, f2, f3;
        f0.x = bf2f((unsigned short)v0[0]); f0.y = bf2f((unsigned short)v0[1]);
        f0.z = bf2f((unsigned short)v0[2]); f0.w = bf2f((unsigned short)v0[3]);
        f1.x = bf2f((unsigned short)v0[4]); f1.y = bf2f((unsigned short)v0[5]);
        f1.z = bf2f((unsigned short)v0[6]); f1.w = bf2f((unsigned short)v0[7]);
        f2.x = bf2f((unsigned short)v1[0]); f2.y = bf2f((unsigned short)v1[1]);
        f2.z = bf2f((unsigned short)v1[2]); f2.w = bf2f((unsigned short)v1[3]);
        f3.x = bf2f((unsigned short)v1[4]); f3.y = bf2f((unsigned short)v1[5]);
        f3.z = bf2f((unsigned short)v1[6]); f3.w = bf2f((unsigned short)v1[7]);
        *(float4*)(dst)      = f0;
        *(float4*)(dst + 4)  = f1;
        *(float4*)(dst + 8)  = f2;
        *(float4*)(dst + 12) = f3;
    }
    __syncthreads();

    const float4* was4 = (const float4*)was;
    float tac[8];
    #pragma unroll
    for (int u = 0; u < 8; ++u) tac[u] = bas[j0 + u];
    for (int k = 0; k < 64; ++k) {
        const float hv = rowbuf[sr][k];
        const float4 wa = was4[k * 8 + (q << 1)];
        const float4 wb = was4[k * 8 + (q << 1) + 1];
        tac[0] += hv * wa.x; tac[1] += hv * wa.y;
        tac[2] += hv * wa.z; tac[3] += hv * wa.w;
        tac[4] += hv * wb.x; tac[5] += hv * wb.y;
        tac[6] += hv * wb.z; tac[7] += hv * wb.w;
    }
    float part = 0.f;
    #pragma unroll
    for (int u = 0; u < 8; ++u) part += fast_tanh(tac[u]) * wa2s[j0 + u];
    float sa = 0.f;
    for (int k = q * 16; k < q * 16 + 16; ++k) sa += fabsf(rowbuf[sr][k]);
    part += __shfl_xor(part, 1);
    part += __shfl_xor(part, 2);
    sa   += __shfl_xor(sa, 1);
    sa   += __shfl_xor(sa, 2);
    if (q == 0) sexp[sr] = (sa > 0.f) ? __expf(part + ba2[0]) : 0.f;
    __syncthreads();

    if (tid < 64) {
        float e = sexp[tid];
        #pragma unroll
        for (int o = 1; o < 64; o <<= 1) e += __shfl_xor(e, o);
        if (tid == 0) pden[p] = e;
    }

    const int pl   = p & 63;
    const int nb0  = pl * 64;
    const int glo  = nb0 / PPG_;
    const int col  = tid & 63, qq = tid >> 6;
    float acc0 = 0.f, acc1 = 0.f;
    for (int r = qq; r < 64; r += 4) {
        const float e = sexp[r];
        const float v = rowbuf[r][col];
        if ((nb0 + r) / PPG_ == glo) acc0 += e * v; else acc1 += e * v;
    }
    rnum[qq][0][col] = acc0;
    rnum[qq][1][col] = acc1;
    __syncthreads();
    if (tid < 128) {
        const int slot = tid >> 6, c2 = tid & 63;
        pnum[((size_t)p * 2 + slot) * 64 + c2] =
            rnum[0][slot][c2] + rnum[1][slot][c2] + rnum[2][slot][c2] + rnum[3][slot][c2];
    }
}

// ============================================================================
// K4: gather grouped from pnum/pden (fused) + conv1 + residual (R20-proven)
// ============================================================================
__global__ __launch_bounds__(256) void k4_conv1(
    const float* __restrict__ pnum, const float* __restrict__ pden,
    const float* __restrict__ c1w, const float* __restrict__ c1b,
    const float* __restrict__ r1w, const float* __restrict__ r1b,
    float* __restrict__ y1raw, float* __restrict__ res1,
    float* __restrict__ b1p, float* __restrict__ b1q)
{
    __shared__ __align__(16) float gs[G_][68];
    __shared__ float cws[30 * 64];
    __shared__ float rws[G_ * 64];
    __shared__ float c1bs[64], r1bs[64];
    __shared__ float red[256];
    __shared__ float dsh;

    const int b = blockIdx.x, tid = threadIdx.x;

    if (tid < 64) {
        float e = pden[b * 64 + tid];
        #pragma unroll
        for (int o = 1; o < 64; o <<= 1) e += __shfl_xor(e, o);
        if (tid == 0) dsh = e;
    }
    for (int i = tid; i < 30 * 64; i += 256) {
        const int ik = i >> 6, o = i & 63;
        cws[i] = c1w[o * 30 + ik];
    }
    for (int i = tid; i < G_ * 64; i += 256) {
        const int ch = i >> 6, o = i & 63;
        rws[i] = r1w[o * G_ + ch];
    }
    if (tid < 64) { c1bs[tid] = c1b[tid]; r1bs[tid] = r1b[tid]; }
    if (tid < G_) { gs[tid][0] = 0.f; gs[tid][65] = 0.f; gs[tid][66] = 0.f; gs[tid][67] = 0.f; }
    __syncthreads();

    const float inv = 1.f / dsh;
    for (int i = tid; i < 640; i += 256) {
        const int ch = i >> 6, col = i & 63;
        int p_lo = (PPG_ * ch) >> 6;
        int p_hi = (PPG_ * (ch + 1) - 1) >> 6;
        if (p_hi > 63) p_hi = 63;
        float acc = 0.f;
        for (int pl = p_lo; pl <= p_hi; ++pl) {
            const int glo = (pl * 64) / PPG_;
            const int slot = (glo == ch) ? 0 : 1;
            acc += pnum[(((size_t)(b * 64 + pl)) * 2 + slot) * 64 + col];
        }
        gs[ch][1 + col] = acc * inv;
    }
    __syncthreads();

    const int o = tid & 63, lq = tid >> 6;
    float acc[16], racc[16];
    #pragma unroll
    for (int s = 0; s < 16; ++s) { acc[s] = c1bs[o]; racc[s] = r1bs[o]; }

    #pragma unroll
    for (int i = 0; i < G_; ++i) {
        const float* row = &gs[i][lq * 16];
        const float4 a0 = *(const float4*)&row[0];
        const float4 a1 = *(const float4*)&row[4];
        const float4 a2 = *(const float4*)&row[8];
        const float4 a3 = *(const float4*)&row[12];
        const float w16 = row[16], w17 = row[17];
        const float win[18] = { a0.x,a0.y,a0.z,a0.w, a1.x,a1.y,a1.z,a1.w,
                                a2.x,a2.y,a2.z,a2.w, a3.x,a3.y,a3.z,a3.w, w16, w17 };
        const float w0 = cws[(i * 3 + 0) * 64 + o];
        const float w1 = cws[(i * 3 + 1) * 64 + o];
        const float w2 = cws[(i * 3 + 2) * 64 + o];
        const float rw = rws[i * 64 + o];
        #pragma unroll
        for (int s = 0; s < 16; ++s) {
            acc[s]  += win[s] * w0 + win[s + 1] * w1 + win[s + 2] * w2;
            racc[s] += win[s + 1] * rw;
        }
    }

    float psum = 0.f, psq = 0.f;
    #pragma unroll
    for (int s = 0; s < 16; ++s) { psum += acc[s]; psq += acc[s] * acc[s]; }

    float* yo = &y1raw[(size_t)(b * 64 + o) * 64 + lq * 16];
    float* ro = &res1 [(size_t)(b * 64 + o) * 64 + lq * 16];
    #pragma unroll
    for (int s4 = 0; s4 < 4; ++s4) {
        float4 v; v.x = acc[s4*4]; v.y = acc[s4*4+1]; v.z = acc[s4*4+2]; v.w = acc[s4*4+3];
        *(float4*)&yo[s4 * 4] = v;
        float4 u; u.x = racc[s4*4]; u.y = racc[s4*4+1]; u.z = racc[s4*4+2]; u.w = racc[s4*4+3];
        *(float4*)&ro[s4 * 4] = u;
    }
    red[tid] = psum; __syncthreads();
    if (tid < 64) b1p[b * 64 + tid] = red[tid] + red[tid + 64] + red[tid + 128] + red[tid + 192];
    __syncthreads();
    red[tid] = psq; __syncthreads();
    if (tid < 64) b1q[b * 64 + tid] = red[tid] + red[tid + 64] + red[tid + 128] + red[tid + 192];
}

// ============================================================================
// K5: BN1 finalize + z1 + conv2 (register-window form, R15-proven)
// ============================================================================
__global__ __launch_bounds__(256) void k5_conv2(
    const float* __restrict__ y1raw, const float* __restrict__ res1,
    const float* __restrict__ b1p, const float* __restrict__ b1q,
    const float* __restrict__ bn1g, const float* __restrict__ bn1b,
    const float* __restrict__ c2w, const float* __restrict__ c2b,
    float* __restrict__ z1, float* __restrict__ y2raw,
    float* __restrict__ b2p, float* __restrict__ b2q)
{
    __shared__ __align__(16) float zs[64][68];
    __shared__ float c2ws[192 * 64];
    __shared__ float s1[64], sh1[64], c2bs[64];
    __shared__ float red[256];

    const int b = blockIdx.x, tid = threadIdx.x;
    if (tid < 64) {
        float sm = 0.f, sq = 0.f;
        for (int blk = 0; blk < 64; ++blk) { sm += b1p[blk * 64 + tid]; sq += b1q[blk * 64 + tid]; }
        const float mean = sm * (1.f / 4096.f);
        const float var  = sq * (1.f / 4096.f) - mean * mean;
        const float sc   = bn1g[tid] * rsqrtf(var + 1e-5f);
        s1[tid] = sc; sh1[tid] = bn1b[tid] - mean * sc;
        zs[tid][0] = 0.f; zs[tid][65] = 0.f;
        c2bs[tid] = c2b[tid];
    }
    for (int i = tid; i < 192 * 64; i += 256) {
        const int ik = i >> 6, o = i & 63;
        c2ws[i] = c2w[o * 192 + ik];
    }
    __syncthreads();
    for (int i = tid; i < 4096; i += 256) {
        const int o = i >> 6, l = i & 63;
        float v = y1raw[(size_t)b * 4096 + i];
        v = fmaxf(0.f, v * s1[o] + sh1[o]) + res1[(size_t)b * 4096 + i];
        z1[(size_t)b * 4096 + i] = v;
        zs[o][1 + l] = v;
    }
    __syncthreads();

    const int o = tid & 63, lq = tid >> 6;
    float acc[16];
    #pragma unroll
    for (int s = 0; s < 16; ++s) acc[s] = c2bs[o];

    #pragma unroll 4
    for (int i = 0; i < 64; ++i) {
        const float* row = &zs[i][lq * 16];
        const float4 a0 = *(const float4*)&row[0];
        const float4 a1 = *(const float4*)&row[4];
        const float4 a2 = *(const float4*)&row[8];
        const float4 a3 = *(const float4*)&row[12];
        const float w16 = row[16], w17 = row[17];
        const float win[18] = { a0.x,a0.y,a0.z,a0.w, a1.x,a1.y,a1.z,a1.w,
                                a2.x,a2.y,a2.z,a2.w, a3.x,a3.y,a3.z,a3.w, w16, w17 };
        const float w0 = c2ws[(i * 3 + 0) * 64 + o];
        const float w1 = c2ws[(i * 3 + 1) * 64 + o];
        const float w2 = c2ws[(i * 3 + 2) * 64 + o];
        #pragma unroll
        for (int s = 0; s < 16; ++s)
            acc[s] += win[s] * w0 + win[s + 1] * w1 + win[s + 2] * w2;
    }

    float psum = 0.f, psq = 0.f;
    #pragma unroll
    for (int s = 0; s < 16; ++s) { psum += acc[s]; psq += acc[s] * acc[s]; }

    float* yo = &y2raw[(size_t)b * 4096 + o * 64 + lq * 16];
    #pragma unroll
    for (int s4 = 0; s4 < 4; ++s4) {
        float4 v; v.x = acc[s4*4]; v.y = acc[s4*4+1]; v.z = acc[s4*4+2]; v.w = acc[s4*4+3];
        *(float4*)&yo[s4 * 4] = v;
    }
    red[tid] = psum; __syncthreads();
    if (tid < 64) b2p[b * 64 + tid] = red[tid] + red[tid + 64] + red[tid + 128] + red[tid + 192];
    __syncthreads();
    red[tid] = psq; __syncthreads();
    if (tid < 64) b2q[b * 64 + tid] = red[tid] + red[tid + 64] + red[tid + 128] + red[tid + 192];
}

// ============================================================================
// K6: finalize BN2, y2 = relu(bn2(y2raw)) + z1; pool over L; logits
// ============================================================================
__global__ __launch_bounds__(256) void k6_final(
    const float* __restrict__ y2raw, const float* __restrict__ z1,
    const float* __restrict__ b2p, const float* __restrict__ b2q,
    const float* __restrict__ bn2g, const float* __restrict__ bn2b,
    const float* __restrict__ Wc, const float* __restrict__ bc,
    float* __restrict__ out)
{
    __shared__ float s2[64], sh2[64];
    __shared__ float red[256];
    __shared__ float pl[64];
    const int b = blockIdx.x, tid = threadIdx.x;
    if (tid < 64) {
        float sm = 0.f, sq = 0.f;
        for (int blk = 0; blk < 64; ++blk) { sm += b2p[blk * 64 + tid]; sq += b2q[blk * 64 + tid]; }
        const float mean = sm * (1.f / 4096.f);
        const float var  = sq * (1.f / 4096.f) - mean * mean;
        const float sc   = bn2g[tid] * rsqrtf(var + 1e-5f);
        s2[tid] = sc; sh2[tid] = bn2b[tid] - mean * sc;
    }
    __syncthreads();
    const int o = tid & 63, lq = tid >> 6;
    float psum = 0.f;
    for (int s = 0; s < 16; ++s) {
        const int l = lq * 16 + s;
        const size_t idx = (size_t)b * 4096 + o * 64 + l;
        psum += fmaxf(0.f, y2raw[idx] * s2[o] + sh2[o]) + z1[idx];
    }
    red[tid] = psum; __syncthreads();
    if (tid < 64) pl[tid] = (red[tid] + red[tid + 64] + red[tid + 128] + red[tid + 192]) * (1.f / 64.f);
    __syncthreads();
    if (tid < 2) {
        float lg = bc[tid];
        for (int o2 = 0; o2 < 64; ++o2) lg += pl[o2] * Wc[o2 * 2 + tid];
        out[b * 2 + tid] = lg;
    }
}

// ============================================================================
extern "C" void kernel_launch(void* const* d_in, const int* in_sizes, int n_in,
                              void* d_out, int out_size, void* d_ws, size_t ws_size,
                              hipStream_t stream)
{
    (void)in_sizes; (void)n_in; (void)out_size; (void)ws_size;
    const float* x    = (const float*)d_in[0];
    const float* Wd   = (const float*)d_in[1];
    const float* bd   = (const float*)d_in[2];
    const float* Wa1  = (const float*)d_in[3];
    const float* ba1  = (const float*)d_in[4];
    const float* Wa2  = (const float*)d_in[5];
    const float* ba2  = (const float*)d_in[6];
    const float* c1w  = (const float*)d_in[7];
    const float* c1b  = (const float*)d_in[8];
    const float* bn1g = (const float*)d_in[9];
    const float* bn1b = (const float*)d_in[10];
    const float* r1w  = (const float*)d_in[11];
    const float* r1b  = (const float*)d_in[12];
    const float* c2w  = (const float*)d_in[13];
    const float* c2b  = (const float*)d_in[14];
    const float* bn2g = (const float*)d_in[15];
    const float* bn2b = (const float*)d_in[16];
    const float* Wc   = (const float*)d_in[17];
    const float* bc   = (const float*)d_in[18];

    float* ws      = (float*)d_ws;
    unsigned short* h = (unsigned short*)(ws + OFF_H);   // bf16 h
    float* pnum    = ws + OFF_PNUM;
    float* pden    = ws + OFF_PDEN;
    float* b1p     = ws + OFF_B1P;
    float* b1q     = ws + OFF_B1Q;
    float* b2p     = ws + OFF_B2P;
    float* b2q     = ws + OFF_B2Q;
    float* y1raw   = ws + OFF_Y1;
    float* res1    = ws + OFF_RES1;
    float* z1      = ws + OFF_Z1;
    float* y2raw   = ws + OFF_Y2;
    unsigned short* WdT = (unsigned short*)(ws + OFF_WDT);

    k0_wdt<<<dim3(128), dim3(256), 0, stream>>>(Wd, WdT);
    k1_gemm<<<dim3(512), dim3(256), 0, stream>>>(x, WdT, bd, h);
    k2a_scores<<<dim3((B_ * N_) / 64), dim3(256), 0, stream>>>(h, Wa1, ba1, Wa2, ba2, pnum, pden);
    k4_conv1<<<dim3(B_), dim3(256), 0, stream>>>(pnum, pden, c1w, c1b, r1w, r1b,
                                                 y1raw, res1, b1p, b1q);
    k5_conv2<<<dim3(B_), dim3(256), 0, stream>>>(y1raw, res1, b1p, b1q, bn1g, bn1b,
                                                 c2w, c2b, z1, y2raw, b2p, b2q);
    k6_final<<<dim3(B_), dim3(256), 0, stream>>>(y2raw, z1, b2p, b2q, bn2g, bn2b,
                                                 Wc, bc, (float*)d_out);
}